// Round 1
// baseline (625.797 us; speedup 1.0000x reference)
//
#include <hip/hip_runtime.h>

#define NN 50000
#define NE 800000
#define D 128

// ---------------- CSR build ----------------

__global__ void count_kernel(const int* __restrict__ dst, int* __restrict__ deg, int E) {
    int e = blockIdx.x * blockDim.x + threadIdx.x;
    if (e < E) atomicAdd(&deg[dst[e]], 1);
}

__global__ __launch_bounds__(1024) void scan_kernel(const int* __restrict__ deg,
        int* __restrict__ rowptr, int* __restrict__ cursor, int n) {
    __shared__ int s[1024];
    int tid = threadIdx.x;
    int chunk = (n + 1023) >> 10;
    int beg = tid * chunk;
    int end = min(beg + chunk, n);
    int sum = 0;
    for (int i = beg; i < end; ++i) sum += deg[i];
    s[tid] = sum;
    __syncthreads();
    for (int off = 1; off < 1024; off <<= 1) {
        int v = (tid >= off) ? s[tid - off] : 0;
        __syncthreads();
        s[tid] += v;
        __syncthreads();
    }
    int base = s[tid] - sum;  // exclusive prefix for this chunk
    for (int i = beg; i < end; ++i) {
        rowptr[i] = base;
        cursor[i] = base;
        base += deg[i];
    }
    if (tid == 1023) rowptr[n] = s[1023];
}

__global__ void fill_kernel(const int* __restrict__ src, const int* __restrict__ dst,
        int* __restrict__ cursor, int* __restrict__ csr_src, int E) {
    int e = blockIdx.x * blockDim.x + threadIdx.x;
    if (e < E) {
        int p = atomicAdd(&cursor[dst[e]], 1);
        csr_src[p] = src[e];
    }
}

// ---------------- mean aggregation (gather over CSR) ----------------

__global__ __launch_bounds__(128) void agg_kernel(const float* __restrict__ X,
        const int* __restrict__ rowptr, const int* __restrict__ csr_src,
        float* __restrict__ out) {
    int n = blockIdx.x;
    int t = threadIdx.x;
    int beg = rowptr[n];
    int end = rowptr[n + 1];
    float acc = 0.0f;
    for (int j = beg; j < end; ++j) {
        int sn = csr_src[j];                 // wave-uniform -> scalar load
        acc += X[(size_t)sn * D + t];        // coalesced 512B row read
    }
    float inv = (end > beg) ? (1.0f / (float)(end - beg)) : 0.0f;
    out[(size_t)n * D + t] = acc * inv;
}

// ---------------- fused dual-GEMM: out = A@Wl + b + X@Wr (opt relu) ----------------

__global__ __launch_bounds__(256) void gemm_kernel(const float* __restrict__ A,
        const float* __restrict__ X, const float* __restrict__ Wl,
        const float* __restrict__ b, const float* __restrict__ Wr,
        float* __restrict__ out, int do_relu, int nrows_total) {
    __shared__ float sWl[D * D];   // 64 KB
    __shared__ float sWr[D * D];   // 64 KB
    __shared__ float sb[D];
    __shared__ float sA[8][D];     // 4 KB
    __shared__ float sX[8][D];     // 4 KB

    for (int i = threadIdx.x; i < D * D / 4; i += 256) {
        ((float4*)sWl)[i] = ((const float4*)Wl)[i];
        ((float4*)sWr)[i] = ((const float4*)Wr)[i];
    }
    if (threadIdx.x < D) sb[threadIdx.x] = b[threadIdx.x];
    __syncthreads();

    int cg = threadIdx.x & 31;   // column group of 4
    int r  = threadIdx.x >> 5;   // row within 8-row tile

    for (int row0 = blockIdx.x * 8; row0 < nrows_total; row0 += gridDim.x * 8) {
        int row = row0 + r;
        if (row < nrows_total) {
            ((float4*)sA[r])[cg] = ((const float4*)(A + (size_t)row * D))[cg];
            ((float4*)sX[r])[cg] = ((const float4*)(X + (size_t)row * D))[cg];
        }
        __syncthreads();
        if (row < nrows_total) {
            float4 acc = make_float4(0.f, 0.f, 0.f, 0.f);
            #pragma unroll 4
            for (int k = 0; k < D; ++k) {
                float a  = sA[r][k];
                float xv = sX[r][k];
                float4 wl = ((const float4*)(sWl + k * D))[cg];
                float4 wr = ((const float4*)(sWr + k * D))[cg];
                acc.x += a * wl.x + xv * wr.x;
                acc.y += a * wl.y + xv * wr.y;
                acc.z += a * wl.z + xv * wr.z;
                acc.w += a * wl.w + xv * wr.w;
            }
            float4 bb = ((const float4*)sb)[cg];
            acc.x += bb.x; acc.y += bb.y; acc.z += bb.z; acc.w += bb.w;
            if (do_relu) {
                acc.x = fmaxf(acc.x, 0.f); acc.y = fmaxf(acc.y, 0.f);
                acc.z = fmaxf(acc.z, 0.f); acc.w = fmaxf(acc.w, 0.f);
            }
            ((float4*)(out + (size_t)row * D))[cg] = acc;
        }
        __syncthreads();
    }
}

// ---------------- launch ----------------

extern "C" void kernel_launch(void* const* d_in, const int* in_sizes, int n_in,
                              void* d_out, int out_size, void* d_ws, size_t ws_size,
                              hipStream_t stream) {
    const float* x   = (const float*)d_in[0];
    const int*   ei  = (const int*)d_in[1];   // int64 in source downcast to int32 by JAX (x64 disabled)
    const float* W1l = (const float*)d_in[2];
    const float* b1  = (const float*)d_in[3];
    const float* W1r = (const float*)d_in[4];
    const float* W2l = (const float*)d_in[5];
    const float* b2  = (const float*)d_in[6];
    const float* W2r = (const float*)d_in[7];
    float* out = (float*)d_out;

    const int N = NN, E = NE;
    const int* src = ei;       // edge_index[0]
    const int* dst = ei + E;   // edge_index[1]

    char* ws = (char*)d_ws;
    size_t off = 0;
    auto alloc = [&](size_t bytes) -> void* {
        void* p = ws + off;
        off += (bytes + 255) & ~(size_t)255;
        return p;
    };
    int* deg    = (int*)alloc((size_t)N * 4);
    int* rowptr = (int*)alloc((size_t)(N + 1) * 4);
    int* cursor = (int*)alloc((size_t)N * 4);
    int* csr    = (int*)alloc((size_t)E * 4);
    float* aggr = (float*)alloc((size_t)N * D * 4);
    float* h    = (float*)alloc((size_t)N * D * 4);

    hipMemsetAsync(deg, 0, (size_t)N * 4, stream);
    count_kernel<<<(E + 255) / 256, 256, 0, stream>>>(dst, deg, E);
    scan_kernel<<<1, 1024, 0, stream>>>(deg, rowptr, cursor, N);
    fill_kernel<<<(E + 255) / 256, 256, 0, stream>>>(src, dst, cursor, csr, E);

    // layer 1
    agg_kernel<<<N, 128, 0, stream>>>(x, rowptr, csr, aggr);
    gemm_kernel<<<256, 256, 0, stream>>>(aggr, x, W1l, b1, W1r, h, 1, N);

    // layer 2
    agg_kernel<<<N, 128, 0, stream>>>(h, rowptr, csr, aggr);
    gemm_kernel<<<256, 256, 0, stream>>>(aggr, h, W2l, b2, W2r, out, 0, N);
}

// Round 2
// 309.447 us; speedup vs baseline: 2.0223x; 2.0223x over previous
//
#include <hip/hip_runtime.h>

#define NN 50000
#define NE 800000
#define D 128

typedef __attribute__((ext_vector_type(8))) short short8;
typedef __attribute__((ext_vector_type(4))) float f32x4;

__device__ inline unsigned short f2bf(float f) {
    unsigned u = __builtin_bit_cast(unsigned, f);
    unsigned r = (u + 0x7fffu + ((u >> 16) & 1u)) >> 16;
    return (unsigned short)r;
}
__device__ inline float bflo(unsigned u) { return __builtin_bit_cast(float, u << 16); }
__device__ inline float bfhi(unsigned u) { return __builtin_bit_cast(float, u & 0xffff0000u); }

// ---------------- CSR build ----------------

__global__ void count_kernel(const int* __restrict__ dst, int* __restrict__ deg, int E) {
    int e = blockIdx.x * blockDim.x + threadIdx.x;
    if (e < E) atomicAdd(&deg[dst[e]], 1);
}

__global__ __launch_bounds__(1024) void scan_kernel(const int* __restrict__ deg,
        int* __restrict__ rowptr, int* __restrict__ cursor, int n) {
    __shared__ int s[1024];
    int tid = threadIdx.x;
    int chunk = (n + 1023) >> 10;
    int beg = tid * chunk;
    int end = min(beg + chunk, n);
    int sum = 0;
    for (int i = beg; i < end; ++i) sum += deg[i];
    s[tid] = sum;
    __syncthreads();
    for (int off = 1; off < 1024; off <<= 1) {
        int v = (tid >= off) ? s[tid - off] : 0;
        __syncthreads();
        s[tid] += v;
        __syncthreads();
    }
    int base = s[tid] - sum;
    for (int i = beg; i < end; ++i) {
        rowptr[i] = base;
        cursor[i] = base;
        base += deg[i];
    }
    if (tid == 1023) rowptr[n] = s[1023];
}

__global__ void fill_kernel(const int* __restrict__ src, const int* __restrict__ dst,
        int* __restrict__ cursor, int* __restrict__ csr_src, int E) {
    int e = blockIdx.x * blockDim.x + threadIdx.x;
    if (e < E) {
        int p = atomicAdd(&cursor[dst[e]], 1);
        csr_src[p] = src[e];
    }
}

// ---------------- fp32 -> bf16 convert ----------------

__global__ void cvt_bf16_kernel(const float* __restrict__ in, unsigned short* __restrict__ out, int n4) {
    int i = blockIdx.x * blockDim.x + threadIdx.x;
    int stride = gridDim.x * blockDim.x;
    for (; i < n4; i += stride) {
        float4 v = ((const float4*)in)[i];
        ushort4 o;
        o.x = f2bf(v.x); o.y = f2bf(v.y); o.z = f2bf(v.z); o.w = f2bf(v.w);
        ((ushort4*)out)[i] = o;
    }
}

// ---------------- pack weights into MFMA B-frag layout ----------------
// For each W (128x128 fp32 row-major [k][n]) produce frag layout:
// frag f = ct*4+kk (ct=col-tile 0..7, kk=k-step 0..3), lane l (0..63):
//   col = ct*16 + (l&15), k = kk*32 + (l>>4)*8 + e, e=0..7
// flat short index: (f*64 + l)*8 + e  -> lane-linear 16B units, LDS conflict-free.

__global__ __launch_bounds__(256) void prep_w_kernel(const float* __restrict__ W0,
        const float* __restrict__ W1, const float* __restrict__ W2,
        const float* __restrict__ W3, unsigned short* __restrict__ O) {
    int t = blockIdx.x * 256 + threadIdx.x;   // 0..8191
    int w = t >> 11;
    int rem = t & 2047;
    int f = rem >> 6, l = rem & 63;
    int ct = f >> 2, kk = f & 3;
    int col = ct * 16 + (l & 15);
    int k0 = kk * 32 + (l >> 4) * 8;
    const float* W = (w == 0) ? W0 : (w == 1) ? W1 : (w == 2) ? W2 : W3;
    unsigned short* o = O + (size_t)w * 16384 + ((size_t)f * 64 + l) * 8;
    #pragma unroll
    for (int e = 0; e < 8; ++e) o[e] = f2bf(W[(k0 + e) * D + col]);
}

// ---------------- dual-output bf16 MFMA GEMM: Y = A@Wl, Z = A@Wr ----------------

__global__ __launch_bounds__(256, 1) void gemm_kernel(const unsigned short* __restrict__ A,
        const unsigned short* __restrict__ WfL, const unsigned short* __restrict__ WfR,
        unsigned short* __restrict__ Yb, unsigned short* __restrict__ Zb, int nrows) {
    __shared__ short8 sW[4096];   // [0..2047]=Wl frags, [2048..4095]=Wr frags (64 KB)

    for (int i = threadIdx.x; i < 2048; i += 256) {
        sW[i]        = ((const short8*)WfL)[i];
        sW[i + 2048] = ((const short8*)WfR)[i];
    }
    __syncthreads();

    int wv = threadIdx.x >> 6, l = threadIdx.x & 63;
    int r15 = l & 15, kg = l >> 4;
    int row0 = blockIdx.x * 128 + wv * 32;

    // A fragments: 2 row-tiles x 4 k-steps, 16B each, direct from global
    short8 a[2][4];
    #pragma unroll
    for (int rt = 0; rt < 2; ++rt) {
        #pragma unroll
        for (int kk = 0; kk < 4; ++kk) {
            int row = row0 + rt * 16 + r15;
            row = min(row, nrows - 1);
            a[rt][kk] = *(const short8*)(A + (size_t)row * D + kk * 32 + kg * 8);
        }
    }

    f32x4 accY[2][8] = {};
    f32x4 accZ[2][8] = {};
    #pragma unroll
    for (int ct = 0; ct < 8; ++ct) {
        #pragma unroll
        for (int kk = 0; kk < 4; ++kk) {
            short8 bL = sW[(ct * 4 + kk) * 64 + l];
            short8 bR = sW[2048 + (ct * 4 + kk) * 64 + l];
            accY[0][ct] = __builtin_amdgcn_mfma_f32_16x16x32_bf16(a[0][kk], bL, accY[0][ct], 0, 0, 0);
            accY[1][ct] = __builtin_amdgcn_mfma_f32_16x16x32_bf16(a[1][kk], bL, accY[1][ct], 0, 0, 0);
            accZ[0][ct] = __builtin_amdgcn_mfma_f32_16x16x32_bf16(a[0][kk], bR, accZ[0][ct], 0, 0, 0);
            accZ[1][ct] = __builtin_amdgcn_mfma_f32_16x16x32_bf16(a[1][kk], bR, accZ[1][ct], 0, 0, 0);
        }
    }

    // C/D layout: col = ct*16 + (lane&15), row = rt*16 + (lane>>4)*4 + i
    #pragma unroll
    for (int rt = 0; rt < 2; ++rt) {
        #pragma unroll
        for (int ct = 0; ct < 8; ++ct) {
            #pragma unroll
            for (int i = 0; i < 4; ++i) {
                int row = row0 + rt * 16 + kg * 4 + i;
                if (row < nrows) {
                    int col = ct * 16 + r15;
                    Yb[(size_t)row * D + col] = f2bf(accY[rt][ct][i]);
                    Zb[(size_t)row * D + col] = f2bf(accZ[rt][ct][i]);
                }
            }
        }
    }
}

// ---------------- mean-aggregate (bf16 gather) + epilogue ----------------
// out[node] = mean_j Y[csr[j]] + bias + Z[node]  (optional relu; bf16 or fp32 out)

template<int RELU, int OUTBF16>
__global__ __launch_bounds__(256) void agg_ep_kernel(const unsigned short* __restrict__ Yb,
        const unsigned short* __restrict__ Zb, const float* __restrict__ bias,
        const int* __restrict__ rowptr, const int* __restrict__ csr,
        void* __restrict__ outp) {
    int lane = threadIdx.x & 63;
    int wv = (blockIdx.x << 2) + (threadIdx.x >> 6);
    int nw = gridDim.x << 2;
    float b0 = bias[lane * 2], b1 = bias[lane * 2 + 1];

    for (int node = wv; node < NN; node += nw) {
        int beg = rowptr[node], end = rowptr[node + 1];
        float a0 = 0.f, a1 = 0.f;
        int j = beg;
        for (; j + 3 < end; j += 4) {
            int s0 = csr[j], s1 = csr[j + 1], s2 = csr[j + 2], s3 = csr[j + 3];
            unsigned u0 = *(const unsigned*)(Yb + (size_t)s0 * D + lane * 2);
            unsigned u1 = *(const unsigned*)(Yb + (size_t)s1 * D + lane * 2);
            unsigned u2 = *(const unsigned*)(Yb + (size_t)s2 * D + lane * 2);
            unsigned u3 = *(const unsigned*)(Yb + (size_t)s3 * D + lane * 2);
            a0 += bflo(u0) + bflo(u1) + bflo(u2) + bflo(u3);
            a1 += bfhi(u0) + bfhi(u1) + bfhi(u2) + bfhi(u3);
        }
        for (; j < end; ++j) {
            unsigned u = *(const unsigned*)(Yb + (size_t)csr[j] * D + lane * 2);
            a0 += bflo(u);
            a1 += bfhi(u);
        }
        float inv = (end > beg) ? 1.f / (float)(end - beg) : 0.f;
        unsigned uz = *(const unsigned*)(Zb + (size_t)node * D + lane * 2);
        float v0 = a0 * inv + b0 + bflo(uz);
        float v1 = a1 * inv + b1 + bfhi(uz);
        if (RELU) { v0 = fmaxf(v0, 0.f); v1 = fmaxf(v1, 0.f); }
        if (OUTBF16) {
            unsigned o = (unsigned)f2bf(v0) | ((unsigned)f2bf(v1) << 16);
            *(unsigned*)((unsigned short*)outp + (size_t)node * D + lane * 2) = o;
        } else {
            float2 o; o.x = v0; o.y = v1;
            *(float2*)((float*)outp + (size_t)node * D + lane * 2) = o;
        }
    }
}

// ---------------- launch ----------------

extern "C" void kernel_launch(void* const* d_in, const int* in_sizes, int n_in,
                              void* d_out, int out_size, void* d_ws, size_t ws_size,
                              hipStream_t stream) {
    const float* x   = (const float*)d_in[0];
    const int*   ei  = (const int*)d_in[1];
    const float* W1l = (const float*)d_in[2];
    const float* b1  = (const float*)d_in[3];
    const float* W1r = (const float*)d_in[4];
    const float* W2l = (const float*)d_in[5];
    const float* b2  = (const float*)d_in[6];
    const float* W2r = (const float*)d_in[7];
    float* out = (float*)d_out;

    const int N = NN, E = NE;
    const int* src = ei;
    const int* dst = ei + E;

    char* ws = (char*)d_ws;
    size_t off = 0;
    auto alloc = [&](size_t bytes) -> void* {
        void* p = ws + off;
        off += (bytes + 255) & ~(size_t)255;
        return p;
    };
    int* deg    = (int*)alloc((size_t)N * 4);
    int* rowptr = (int*)alloc((size_t)(N + 1) * 4);
    int* cursor = (int*)alloc((size_t)N * 4);
    int* csr    = (int*)alloc((size_t)E * 4);
    unsigned short* xb  = (unsigned short*)alloc((size_t)N * D * 2);  // also reused as h
    unsigned short* Yb  = (unsigned short*)alloc((size_t)N * D * 2);
    unsigned short* Zb  = (unsigned short*)alloc((size_t)N * D * 2);
    unsigned short* wf  = (unsigned short*)alloc((size_t)4 * 16384 * 2);  // frag-packed W1l,W1r,W2l,W2r

    // CSR build
    hipMemsetAsync(deg, 0, (size_t)N * 4, stream);
    count_kernel<<<(E + 255) / 256, 256, 0, stream>>>(dst, deg, E);
    scan_kernel<<<1, 1024, 0, stream>>>(deg, rowptr, cursor, N);
    fill_kernel<<<(E + 255) / 256, 256, 0, stream>>>(src, dst, cursor, csr, E);

    // prep: x -> bf16, weights -> frag layout
    cvt_bf16_kernel<<<2048, 256, 0, stream>>>(x, xb, N * D / 4);
    prep_w_kernel<<<32, 256, 0, stream>>>(W1l, W1r, W2l, W2r, wf);

    unsigned short* wf1l = wf;
    unsigned short* wf1r = wf + 16384;
    unsigned short* wf2l = wf + 2 * 16384;
    unsigned short* wf2r = wf + 3 * 16384;

    int gblocks = (N + 127) / 128;

    // layer 1: Y1 = x@W1l, Z1 = x@W1r; h = relu(mean-agg(Y1) + b1 + Z1)  [h aliases xb]
    gemm_kernel<<<gblocks, 256, 0, stream>>>(xb, wf1l, wf1r, Yb, Zb, N);
    agg_ep_kernel<1, 1><<<2048, 256, 0, stream>>>(Yb, Zb, b1, rowptr, csr, xb);

    // layer 2: Y2 = h@W2l, Z2 = h@W2r; out = mean-agg(Y2) + b2 + Z2
    gemm_kernel<<<gblocks, 256, 0, stream>>>(xb, wf2l, wf2r, Yb, Zb, N);
    agg_ep_kernel<0, 0><<<2048, 256, 0, stream>>>(Yb, Zb, b2, rowptr, csr, out);
}

// Round 3
// 220.124 us; speedup vs baseline: 2.8429x; 1.4058x over previous
//
#include <hip/hip_runtime.h>

#define NN 50000
#define NE 800000
#define D 128

typedef __attribute__((ext_vector_type(8))) short short8;
typedef __attribute__((ext_vector_type(4))) float f32x4;

__device__ inline unsigned short f2bf(float f) {
    unsigned u = __builtin_bit_cast(unsigned, f);
    unsigned r = (u + 0x7fffu + ((u >> 16) & 1u)) >> 16;
    return (unsigned short)r;
}
__device__ inline float bflo(unsigned u) { return __builtin_bit_cast(float, u << 16); }
__device__ inline float bfhi(unsigned u) { return __builtin_bit_cast(float, u & 0xffff0000u); }

// ---------------- CSR build ----------------

__global__ void count_kernel(const int* __restrict__ dst, int* __restrict__ deg, int E) {
    int e = blockIdx.x * blockDim.x + threadIdx.x;
    if (e < E) atomicAdd(&deg[dst[e]], 1);
}

// two-level scan: partial sums -> scan of sums -> local scan + offset
__global__ __launch_bounds__(256) void partial_kernel(const int* __restrict__ deg,
        int* __restrict__ bsum, int n) {
    __shared__ int s[256];
    int t = threadIdx.x;
    int i = blockIdx.x * 256 + t;
    s[t] = (i < n) ? deg[i] : 0;
    __syncthreads();
    #pragma unroll
    for (int off = 128; off > 0; off >>= 1) {
        if (t < off) s[t] += s[t + off];
        __syncthreads();
    }
    if (t == 0) bsum[blockIdx.x] = s[0];
}

__global__ __launch_bounds__(256) void scanb_kernel(const int* __restrict__ bsum,
        int* __restrict__ boff, int nblk, int* __restrict__ rowptr, int n) {
    __shared__ int s[256];
    int t = threadIdx.x;
    int v = (t < nblk) ? bsum[t] : 0;
    s[t] = v;
    __syncthreads();
    #pragma unroll
    for (int off = 1; off < 256; off <<= 1) {
        int u = (t >= off) ? s[t - off] : 0;
        __syncthreads();
        s[t] += u;
        __syncthreads();
    }
    if (t < nblk) boff[t] = s[t] - v;   // exclusive
    if (t == 255) rowptr[n] = s[255];   // total = E
}

__global__ __launch_bounds__(256) void scan2_kernel(const int* __restrict__ deg,
        const int* __restrict__ boff, int* __restrict__ rowptr,
        int* __restrict__ cursor, int n) {
    __shared__ int s[256];
    int t = threadIdx.x;
    int i = blockIdx.x * 256 + t;
    int v = (i < n) ? deg[i] : 0;
    s[t] = v;
    __syncthreads();
    #pragma unroll
    for (int off = 1; off < 256; off <<= 1) {
        int u = (t >= off) ? s[t - off] : 0;
        __syncthreads();
        s[t] += u;
        __syncthreads();
    }
    if (i < n) {
        int excl = s[t] - v + boff[blockIdx.x];
        rowptr[i] = excl;
        cursor[i] = excl;
    }
}

__global__ void fill_kernel(const int* __restrict__ src, const int* __restrict__ dst,
        int* __restrict__ cursor, int* __restrict__ csr_src, int E) {
    int e = blockIdx.x * blockDim.x + threadIdx.x;
    if (e < E) {
        int p = atomicAdd(&cursor[dst[e]], 1);
        csr_src[p] = src[e];
    }
}

// ---------------- fp32 -> bf16 convert ----------------

__global__ void cvt_bf16_kernel(const float* __restrict__ in, unsigned short* __restrict__ out, int n4) {
    int i = blockIdx.x * blockDim.x + threadIdx.x;
    int stride = gridDim.x * blockDim.x;
    for (; i < n4; i += stride) {
        float4 v = ((const float4*)in)[i];
        ushort4 o;
        o.x = f2bf(v.x); o.y = f2bf(v.y); o.z = f2bf(v.z); o.w = f2bf(v.w);
        ((ushort4*)out)[i] = o;
    }
}

// ---------------- pack weights into MFMA B-frag layout ----------------
// frag f = ct*4+kk, lane l: col = ct*16+(l&15), k = kk*32+(l>>4)*8+e
// flat short index (f*64+l)*8+e -> lane-linear 16B units, LDS conflict-free.

__global__ __launch_bounds__(256) void prep_w_kernel(const float* __restrict__ W0,
        const float* __restrict__ W1, const float* __restrict__ W2,
        const float* __restrict__ W3, unsigned short* __restrict__ O) {
    int t = blockIdx.x * 256 + threadIdx.x;   // 0..8191
    int w = t >> 11;
    int rem = t & 2047;
    int f = rem >> 6, l = rem & 63;
    int ct = f >> 2, kk = f & 3;
    int col = ct * 16 + (l & 15);
    int k0 = kk * 32 + (l >> 4) * 8;
    const float* W = (w == 0) ? W0 : (w == 1) ? W1 : (w == 2) ? W2 : W3;
    unsigned short* o = O + (size_t)w * 16384 + ((size_t)f * 64 + l) * 8;
    #pragma unroll
    for (int e = 0; e < 8; ++e) o[e] = f2bf(W[(k0 + e) * D + col]);
}

// ---------------- dual-output bf16 MFMA GEMM: Y = A@Wl, Z = A@Wr ----------------

__global__ __launch_bounds__(256, 1) void gemm_kernel(const unsigned short* __restrict__ A,
        const unsigned short* __restrict__ WfL, const unsigned short* __restrict__ WfR,
        unsigned short* __restrict__ Yb, unsigned short* __restrict__ Zb, int nrows) {
    __shared__ short8 sW[4096];   // Wl frags | Wr frags (64 KB)

    for (int i = threadIdx.x; i < 2048; i += 256) {
        sW[i]        = ((const short8*)WfL)[i];
        sW[i + 2048] = ((const short8*)WfR)[i];
    }
    __syncthreads();

    int wv = threadIdx.x >> 6, l = threadIdx.x & 63;
    int r15 = l & 15, kg = l >> 4;
    int row0 = blockIdx.x * 128 + wv * 32;

    short8 a[2][4];
    #pragma unroll
    for (int rt = 0; rt < 2; ++rt) {
        #pragma unroll
        for (int kk = 0; kk < 4; ++kk) {
            int row = row0 + rt * 16 + r15;
            row = min(row, nrows - 1);
            a[rt][kk] = *(const short8*)(A + (size_t)row * D + kk * 32 + kg * 8);
        }
    }

    f32x4 accY[2][8] = {};
    f32x4 accZ[2][8] = {};
    #pragma unroll
    for (int ct = 0; ct < 8; ++ct) {
        #pragma unroll
        for (int kk = 0; kk < 4; ++kk) {
            short8 bL = sW[(ct * 4 + kk) * 64 + l];
            short8 bR = sW[2048 + (ct * 4 + kk) * 64 + l];
            accY[0][ct] = __builtin_amdgcn_mfma_f32_16x16x32_bf16(a[0][kk], bL, accY[0][ct], 0, 0, 0);
            accY[1][ct] = __builtin_amdgcn_mfma_f32_16x16x32_bf16(a[1][kk], bL, accY[1][ct], 0, 0, 0);
            accZ[0][ct] = __builtin_amdgcn_mfma_f32_16x16x32_bf16(a[0][kk], bR, accZ[0][ct], 0, 0, 0);
            accZ[1][ct] = __builtin_amdgcn_mfma_f32_16x16x32_bf16(a[1][kk], bR, accZ[1][ct], 0, 0, 0);
        }
    }

    // C/D: col = ct*16+(lane&15), row = rt*16+(lane>>4)*4+i
    #pragma unroll
    for (int rt = 0; rt < 2; ++rt) {
        #pragma unroll
        for (int ct = 0; ct < 8; ++ct) {
            #pragma unroll
            for (int i = 0; i < 4; ++i) {
                int row = row0 + rt * 16 + kg * 4 + i;
                if (row < nrows) {
                    int col = ct * 16 + r15;
                    Yb[(size_t)row * D + col] = f2bf(accY[rt][ct][i]);
                    Zb[(size_t)row * D + col] = f2bf(accZ[rt][ct][i]);
                }
            }
        }
    }
}

// ---------------- mean-aggregate (bf16 gather) + epilogue ----------------

template<int RELU, int OUTBF16>
__global__ __launch_bounds__(256) void agg_ep_kernel(const unsigned short* __restrict__ Yb,
        const unsigned short* __restrict__ Zb, const float* __restrict__ bias,
        const int* __restrict__ rowptr, const int* __restrict__ csr,
        void* __restrict__ outp) {
    int lane = threadIdx.x & 63;
    int wv = (blockIdx.x << 2) + (threadIdx.x >> 6);
    int nw = gridDim.x << 2;
    float b0 = bias[lane * 2], b1 = bias[lane * 2 + 1];

    for (int node = wv; node < NN; node += nw) {
        int beg = rowptr[node], end = rowptr[node + 1];
        float a0 = 0.f, a1 = 0.f;
        int j = beg;
        for (; j + 3 < end; j += 4) {
            int s0 = csr[j], s1 = csr[j + 1], s2 = csr[j + 2], s3 = csr[j + 3];
            unsigned u0 = *(const unsigned*)(Yb + (size_t)s0 * D + lane * 2);
            unsigned u1 = *(const unsigned*)(Yb + (size_t)s1 * D + lane * 2);
            unsigned u2 = *(const unsigned*)(Yb + (size_t)s2 * D + lane * 2);
            unsigned u3 = *(const unsigned*)(Yb + (size_t)s3 * D + lane * 2);
            a0 += bflo(u0) + bflo(u1) + bflo(u2) + bflo(u3);
            a1 += bfhi(u0) + bfhi(u1) + bfhi(u2) + bfhi(u3);
        }
        for (; j < end; ++j) {
            unsigned u = *(const unsigned*)(Yb + (size_t)csr[j] * D + lane * 2);
            a0 += bflo(u);
            a1 += bfhi(u);
        }
        float inv = (end > beg) ? 1.f / (float)(end - beg) : 0.f;
        unsigned uz = *(const unsigned*)(Zb + (size_t)node * D + lane * 2);
        float v0 = a0 * inv + b0 + bflo(uz);
        float v1 = a1 * inv + b1 + bfhi(uz);
        if (RELU) { v0 = fmaxf(v0, 0.f); v1 = fmaxf(v1, 0.f); }
        if (OUTBF16) {
            unsigned o = (unsigned)f2bf(v0) | ((unsigned)f2bf(v1) << 16);
            *(unsigned*)((unsigned short*)outp + (size_t)node * D + lane * 2) = o;
        } else {
            float2 o; o.x = v0; o.y = v1;
            *(float2*)((float*)outp + (size_t)node * D + lane * 2) = o;
        }
    }
}

// ---------------- launch ----------------

extern "C" void kernel_launch(void* const* d_in, const int* in_sizes, int n_in,
                              void* d_out, int out_size, void* d_ws, size_t ws_size,
                              hipStream_t stream) {
    const float* x   = (const float*)d_in[0];
    const int*   ei  = (const int*)d_in[1];
    const float* W1l = (const float*)d_in[2];
    const float* b1  = (const float*)d_in[3];
    const float* W1r = (const float*)d_in[4];
    const float* W2l = (const float*)d_in[5];
    const float* b2  = (const float*)d_in[6];
    const float* W2r = (const float*)d_in[7];
    float* out = (float*)d_out;

    const int N = NN, E = NE;
    const int* src = ei;
    const int* dst = ei + E;

    char* ws = (char*)d_ws;
    size_t off = 0;
    auto alloc = [&](size_t bytes) -> void* {
        void* p = ws + off;
        off += (bytes + 255) & ~(size_t)255;
        return p;
    };
    int* deg    = (int*)alloc((size_t)N * 4);
    int* rowptr = (int*)alloc((size_t)(N + 1) * 4);
    int* cursor = (int*)alloc((size_t)N * 4);
    int* csr    = (int*)alloc((size_t)E * 4);
    int* bsum   = (int*)alloc(256 * 4);
    int* boff   = (int*)alloc(256 * 4);
    unsigned short* xb  = (unsigned short*)alloc((size_t)N * D * 2);  // reused as h
    unsigned short* Yb  = (unsigned short*)alloc((size_t)N * D * 2);
    unsigned short* Zb  = (unsigned short*)alloc((size_t)N * D * 2);
    unsigned short* wf  = (unsigned short*)alloc((size_t)4 * 16384 * 2);

    const int nblk = (N + 255) / 256;   // 196

    // CSR build
    hipMemsetAsync(deg, 0, (size_t)N * 4, stream);
    count_kernel<<<(E + 255) / 256, 256, 0, stream>>>(dst, deg, E);
    partial_kernel<<<nblk, 256, 0, stream>>>(deg, bsum, N);
    scanb_kernel<<<1, 256, 0, stream>>>(bsum, boff, nblk, rowptr, N);
    scan2_kernel<<<nblk, 256, 0, stream>>>(deg, boff, rowptr, cursor, N);
    fill_kernel<<<(E + 255) / 256, 256, 0, stream>>>(src, dst, cursor, csr, E);

    // prep
    cvt_bf16_kernel<<<2048, 256, 0, stream>>>(x, xb, N * D / 4);
    prep_w_kernel<<<32, 256, 0, stream>>>(W1l, W1r, W2l, W2r, wf);

    unsigned short* wf1l = wf;
    unsigned short* wf1r = wf + 16384;
    unsigned short* wf2l = wf + 2 * 16384;
    unsigned short* wf2r = wf + 3 * 16384;

    int gblocks = (N + 127) / 128;

    // layer 1
    gemm_kernel<<<gblocks, 256, 0, stream>>>(xb, wf1l, wf1r, Yb, Zb, N);
    agg_ep_kernel<1, 1><<<2048, 256, 0, stream>>>(Yb, Zb, b1, rowptr, csr, xb);

    // layer 2
    gemm_kernel<<<gblocks, 256, 0, stream>>>(xb, wf2l, wf2r, Yb, Zb, N);
    agg_ep_kernel<0, 0><<<2048, 256, 0, stream>>>(Yb, Zb, b2, rowptr, csr, out);
}

// Round 4
// 209.893 us; speedup vs baseline: 2.9815x; 1.0487x over previous
//
#include <hip/hip_runtime.h>

#define NN 50000
#define NE 800000
#define D 128
#define NSEG 8
#define SEGSZ 6250   // NN / NSEG

typedef __attribute__((ext_vector_type(8))) short short8;
typedef __attribute__((ext_vector_type(4))) float f32x4;

__device__ inline unsigned short f2bf(float f) {
    unsigned u = __builtin_bit_cast(unsigned, f);
    unsigned r = (u + 0x7fffu + ((u >> 16) & 1u)) >> 16;
    return (unsigned short)r;
}
__device__ inline float bflo(unsigned u) { return __builtin_bit_cast(float, u << 16); }
__device__ inline float bfhi(unsigned u) { return __builtin_bit_cast(float, u & 0xffff0000u); }

// ---------------- CSR build (XCD-segment-partitioned) ----------------
// Segment g handled only by blocks with blockIdx&7==g -> atomics + csr writes
// for each deg/cursor/csr region originate from one XCD; lines stay in its L2.

__global__ __launch_bounds__(256) void count_part_kernel(const int* __restrict__ dst,
        int* __restrict__ deg, int E, int perChunk) {
    int seg = blockIdx.x & 7;
    int chunk = blockIdx.x >> 3;
    int lo = seg * SEGSZ, hi = lo + SEGSZ;
    int beg = chunk * perChunk;
    int end = min(beg + perChunk, E);
    for (int e = beg + threadIdx.x; e < end; e += 256) {
        int d = dst[e];
        if (d >= lo && d < hi) atomicAdd(&deg[d], 1);
    }
}

__global__ __launch_bounds__(256) void fill_part_kernel(const int* __restrict__ src,
        const int* __restrict__ dst, int* __restrict__ cursor,
        int* __restrict__ csr_src, int E, int perChunk) {
    int seg = blockIdx.x & 7;
    int chunk = blockIdx.x >> 3;
    int lo = seg * SEGSZ, hi = lo + SEGSZ;
    int beg = chunk * perChunk;
    int end = min(beg + perChunk, E);
    for (int e = beg + threadIdx.x; e < end; e += 256) {
        int d = dst[e];
        if (d >= lo && d < hi) {
            int p = atomicAdd(&cursor[d], 1);
            csr_src[p] = src[e];
        }
    }
}

// two-level scan: partial sums -> scan of sums -> local scan + offset
__global__ __launch_bounds__(256) void partial_kernel(const int* __restrict__ deg,
        int* __restrict__ bsum, int n) {
    __shared__ int s[256];
    int t = threadIdx.x;
    int i = blockIdx.x * 256 + t;
    s[t] = (i < n) ? deg[i] : 0;
    __syncthreads();
    #pragma unroll
    for (int off = 128; off > 0; off >>= 1) {
        if (t < off) s[t] += s[t + off];
        __syncthreads();
    }
    if (t == 0) bsum[blockIdx.x] = s[0];
}

__global__ __launch_bounds__(256) void scanb_kernel(const int* __restrict__ bsum,
        int* __restrict__ boff, int nblk, int* __restrict__ rowptr, int n) {
    __shared__ int s[256];
    int t = threadIdx.x;
    int v = (t < nblk) ? bsum[t] : 0;
    s[t] = v;
    __syncthreads();
    #pragma unroll
    for (int off = 1; off < 256; off <<= 1) {
        int u = (t >= off) ? s[t - off] : 0;
        __syncthreads();
        s[t] += u;
        __syncthreads();
    }
    if (t < nblk) boff[t] = s[t] - v;
    if (t == 255) rowptr[n] = s[255];
}

__global__ __launch_bounds__(256) void scan2_kernel(const int* __restrict__ deg,
        const int* __restrict__ boff, int* __restrict__ rowptr,
        int* __restrict__ cursor, int n) {
    __shared__ int s[256];
    int t = threadIdx.x;
    int i = blockIdx.x * 256 + t;
    int v = (i < n) ? deg[i] : 0;
    s[t] = v;
    __syncthreads();
    #pragma unroll
    for (int off = 1; off < 256; off <<= 1) {
        int u = (t >= off) ? s[t - off] : 0;
        __syncthreads();
        s[t] += u;
        __syncthreads();
    }
    if (i < n) {
        int excl = s[t] - v + boff[blockIdx.x];
        rowptr[i] = excl;
        cursor[i] = excl;
    }
}

// ---------------- pack weights into MFMA B-frag layout ----------------
// frag f = ct*4+kk, lane l: col = ct*16+(l&15), k = kk*32+(l>>4)*8+e
// flat short index (f*64+l)*8+e -> lane-linear 16B units, LDS conflict-free.

__global__ __launch_bounds__(256) void prep_w_kernel(const float* __restrict__ W0,
        const float* __restrict__ W1, const float* __restrict__ W2,
        const float* __restrict__ W3, unsigned short* __restrict__ O) {
    int t = blockIdx.x * 256 + threadIdx.x;   // 0..8191
    int w = t >> 11;
    int rem = t & 2047;
    int f = rem >> 6, l = rem & 63;
    int ct = f >> 2, kk = f & 3;
    int col = ct * 16 + (l & 15);
    int k0 = kk * 32 + (l >> 4) * 8;
    const float* W = (w == 0) ? W0 : (w == 1) ? W1 : (w == 2) ? W2 : W3;
    unsigned short* o = O + (size_t)w * 16384 + ((size_t)f * 64 + l) * 8;
    #pragma unroll
    for (int e = 0; e < 8; ++e) o[e] = f2bf(W[(k0 + e) * D + col]);
}

// ---------------- dual-output bf16 MFMA GEMM: Y = A@Wl, Z = A@Wr ----------------
// AFP32: A is fp32 row-major (converted to bf16 frags in-register)

template<int AFP32>
__global__ __launch_bounds__(256, 1) void gemm_kernel(const void* __restrict__ Av,
        const unsigned short* __restrict__ WfL, const unsigned short* __restrict__ WfR,
        unsigned short* __restrict__ Yb, unsigned short* __restrict__ Zb, int nrows) {
    __shared__ short8 sW[4096];   // Wl frags | Wr frags (64 KB)

    for (int i = threadIdx.x; i < 2048; i += 256) {
        sW[i]        = ((const short8*)WfL)[i];
        sW[i + 2048] = ((const short8*)WfR)[i];
    }
    __syncthreads();

    int wv = threadIdx.x >> 6, l = threadIdx.x & 63;
    int r15 = l & 15, kg = l >> 4;
    int row0 = blockIdx.x * 128 + wv * 32;

    short8 a[2][4];
    #pragma unroll
    for (int rt = 0; rt < 2; ++rt) {
        #pragma unroll
        for (int kk = 0; kk < 4; ++kk) {
            int row = row0 + rt * 16 + r15;
            row = min(row, nrows - 1);
            int off = kk * 32 + kg * 8;
            if (AFP32) {
                const float* A = (const float*)Av;
                float4 p = *(const float4*)(A + (size_t)row * D + off);
                float4 q = *(const float4*)(A + (size_t)row * D + off + 4);
                short8 v;
                v[0] = (short)f2bf(p.x); v[1] = (short)f2bf(p.y);
                v[2] = (short)f2bf(p.z); v[3] = (short)f2bf(p.w);
                v[4] = (short)f2bf(q.x); v[5] = (short)f2bf(q.y);
                v[6] = (short)f2bf(q.z); v[7] = (short)f2bf(q.w);
                a[rt][kk] = v;
            } else {
                const unsigned short* A = (const unsigned short*)Av;
                a[rt][kk] = *(const short8*)(A + (size_t)row * D + off);
            }
        }
    }

    f32x4 accY[2][8] = {};
    f32x4 accZ[2][8] = {};
    #pragma unroll
    for (int ct = 0; ct < 8; ++ct) {
        #pragma unroll
        for (int kk = 0; kk < 4; ++kk) {
            short8 bL = sW[(ct * 4 + kk) * 64 + l];
            short8 bR = sW[2048 + (ct * 4 + kk) * 64 + l];
            accY[0][ct] = __builtin_amdgcn_mfma_f32_16x16x32_bf16(a[0][kk], bL, accY[0][ct], 0, 0, 0);
            accY[1][ct] = __builtin_amdgcn_mfma_f32_16x16x32_bf16(a[1][kk], bL, accY[1][ct], 0, 0, 0);
            accZ[0][ct] = __builtin_amdgcn_mfma_f32_16x16x32_bf16(a[0][kk], bR, accZ[0][ct], 0, 0, 0);
            accZ[1][ct] = __builtin_amdgcn_mfma_f32_16x16x32_bf16(a[1][kk], bR, accZ[1][ct], 0, 0, 0);
        }
    }

    // C/D: col = ct*16+(lane&15), row = rt*16+(lane>>4)*4+i
    #pragma unroll
    for (int rt = 0; rt < 2; ++rt) {
        #pragma unroll
        for (int ct = 0; ct < 8; ++ct) {
            #pragma unroll
            for (int i = 0; i < 4; ++i) {
                int row = row0 + rt * 16 + kg * 4 + i;
                if (row < nrows) {
                    int col = ct * 16 + r15;
                    Yb[(size_t)row * D + col] = f2bf(accY[rt][ct][i]);
                    Zb[(size_t)row * D + col] = f2bf(accZ[rt][ct][i]);
                }
            }
        }
    }
}

// ---------------- mean-aggregate (bf16 gather) + epilogue ----------------

template<int RELU, int OUTBF16>
__global__ __launch_bounds__(256) void agg_ep_kernel(const unsigned short* __restrict__ Yb,
        const unsigned short* __restrict__ Zb, const float* __restrict__ bias,
        const int* __restrict__ rowptr, const int* __restrict__ csr,
        void* __restrict__ outp) {
    int lane = threadIdx.x & 63;
    int wv = (blockIdx.x << 2) + (threadIdx.x >> 6);
    int nw = gridDim.x << 2;
    float b0 = bias[lane * 2], b1 = bias[lane * 2 + 1];

    for (int node = wv; node < NN; node += nw) {
        int beg = rowptr[node], end = rowptr[node + 1];
        float a0 = 0.f, a1 = 0.f;
        int j = beg;
        for (; j + 3 < end; j += 4) {
            int s0 = csr[j], s1 = csr[j + 1], s2 = csr[j + 2], s3 = csr[j + 3];
            unsigned u0 = *(const unsigned*)(Yb + (size_t)s0 * D + lane * 2);
            unsigned u1 = *(const unsigned*)(Yb + (size_t)s1 * D + lane * 2);
            unsigned u2 = *(const unsigned*)(Yb + (size_t)s2 * D + lane * 2);
            unsigned u3 = *(const unsigned*)(Yb + (size_t)s3 * D + lane * 2);
            a0 += bflo(u0) + bflo(u1) + bflo(u2) + bflo(u3);
            a1 += bfhi(u0) + bfhi(u1) + bfhi(u2) + bfhi(u3);
        }
        for (; j < end; ++j) {
            unsigned u = *(const unsigned*)(Yb + (size_t)csr[j] * D + lane * 2);
            a0 += bflo(u);
            a1 += bfhi(u);
        }
        float inv = (end > beg) ? 1.f / (float)(end - beg) : 0.f;
        unsigned uz = *(const unsigned*)(Zb + (size_t)node * D + lane * 2);
        float v0 = a0 * inv + b0 + bflo(uz);
        float v1 = a1 * inv + b1 + bfhi(uz);
        if (RELU) { v0 = fmaxf(v0, 0.f); v1 = fmaxf(v1, 0.f); }
        if (OUTBF16) {
            unsigned o = (unsigned)f2bf(v0) | ((unsigned)f2bf(v1) << 16);
            *(unsigned*)((unsigned short*)outp + (size_t)node * D + lane * 2) = o;
        } else {
            float2 o; o.x = v0; o.y = v1;
            *(float2*)((float*)outp + (size_t)node * D + lane * 2) = o;
        }
    }
}

// ---------------- launch ----------------

extern "C" void kernel_launch(void* const* d_in, const int* in_sizes, int n_in,
                              void* d_out, int out_size, void* d_ws, size_t ws_size,
                              hipStream_t stream) {
    const float* x   = (const float*)d_in[0];
    const int*   ei  = (const int*)d_in[1];
    const float* W1l = (const float*)d_in[2];
    const float* b1  = (const float*)d_in[3];
    const float* W1r = (const float*)d_in[4];
    const float* W2l = (const float*)d_in[5];
    const float* b2  = (const float*)d_in[6];
    const float* W2r = (const float*)d_in[7];
    float* out = (float*)d_out;

    const int N = NN, E = NE;
    const int* src = ei;
    const int* dst = ei + E;

    char* ws = (char*)d_ws;
    size_t off = 0;
    auto alloc = [&](size_t bytes) -> void* {
        void* p = ws + off;
        off += (bytes + 255) & ~(size_t)255;
        return p;
    };
    int* deg    = (int*)alloc((size_t)N * 4);
    int* rowptr = (int*)alloc((size_t)(N + 1) * 4);
    int* cursor = (int*)alloc((size_t)N * 4);
    int* csr    = (int*)alloc((size_t)E * 4);
    int* bsum   = (int*)alloc(256 * 4);
    int* boff   = (int*)alloc(256 * 4);
    unsigned short* hb  = (unsigned short*)alloc((size_t)N * D * 2);
    unsigned short* Yb  = (unsigned short*)alloc((size_t)N * D * 2);
    unsigned short* Zb  = (unsigned short*)alloc((size_t)N * D * 2);
    unsigned short* wf  = (unsigned short*)alloc((size_t)4 * 16384 * 2);

    const int nblk = (N + 255) / 256;        // 196
    const int chunksPerSeg = 64;
    const int perChunk = (E + chunksPerSeg - 1) / chunksPerSeg;  // 12500
    const int partGrid = NSEG * chunksPerSeg;                    // 512

    // CSR build (XCD-partitioned atomics)
    hipMemsetAsync(deg, 0, (size_t)N * 4, stream);
    count_part_kernel<<<partGrid, 256, 0, stream>>>(dst, deg, E, perChunk);
    partial_kernel<<<nblk, 256, 0, stream>>>(deg, bsum, N);
    scanb_kernel<<<1, 256, 0, stream>>>(bsum, boff, nblk, rowptr, N);
    scan2_kernel<<<nblk, 256, 0, stream>>>(deg, boff, rowptr, cursor, N);
    fill_part_kernel<<<partGrid, 256, 0, stream>>>(src, dst, cursor, csr, E, perChunk);

    // weights -> frag layout
    prep_w_kernel<<<32, 256, 0, stream>>>(W1l, W1r, W2l, W2r, wf);

    unsigned short* wf1l = wf;
    unsigned short* wf1r = wf + 16384;
    unsigned short* wf2l = wf + 2 * 16384;
    unsigned short* wf2r = wf + 3 * 16384;

    int gblocks = (N + 127) / 128;

    // layer 1 (fp32 x consumed directly by gemm)
    gemm_kernel<1><<<gblocks, 256, 0, stream>>>(x, wf1l, wf1r, Yb, Zb, N);
    agg_ep_kernel<1, 1><<<2048, 256, 0, stream>>>(Yb, Zb, b1, rowptr, csr, hb);

    // layer 2
    gemm_kernel<0><<<gblocks, 256, 0, stream>>>(hb, wf2l, wf2r, Yb, Zb, N);
    agg_ep_kernel<0, 0><<<2048, 256, 0, stream>>>(Yb, Zb, b2, rowptr, csr, out);
}